// Round 10
// baseline (381.453 us; speedup 1.0000x reference)
//
#include <hip/hip_runtime.h>
#include <hip/hip_fp16.h>
#include <math.h>

#define NSEG 126

__device__ __forceinline__ unsigned bitrev8(unsigned v) { return __brev(v) >> 24; }

// ---------------------------------------------------------------------------
// K interleaved register-resident 256-point DIF FFTs per wave (proven core).
// ---------------------------------------------------------------------------
template <int K>
__device__ __forceinline__ void fftK(float2 x[][4], int lane) {
    const float PI = 3.14159265358979323846f;
    {   // stage M=256
        float s, c;
        __sincosf(-PI * (float)lane * (1.0f / 128.0f), &s, &c);
        #pragma unroll
        for (int k = 0; k < K; k++) {
            float2 u, t, d;
            u = x[k][0]; t = x[k][2];
            x[k][0] = make_float2(u.x + t.x, u.y + t.y);
            d = make_float2(u.x - t.x, u.y - t.y);
            x[k][2] = make_float2(d.x * c - d.y * s, d.x * s + d.y * c);
            u = x[k][1]; t = x[k][3];
            x[k][1] = make_float2(u.x + t.x, u.y + t.y);
            d = make_float2(u.x - t.x, u.y - t.y);
            x[k][3] = make_float2(d.x * s + d.y * c, -d.x * c + d.y * s);
        }
    }
    {   // stage M=128
        float s, c;
        __sincosf(-PI * (float)lane * (1.0f / 64.0f), &s, &c);
        #pragma unroll
        for (int k = 0; k < K; k++) {
            float2 u, t, d;
            u = x[k][0]; t = x[k][1];
            x[k][0] = make_float2(u.x + t.x, u.y + t.y);
            d = make_float2(u.x - t.x, u.y - t.y);
            x[k][1] = make_float2(d.x * c - d.y * s, d.x * s + d.y * c);
            u = x[k][2]; t = x[k][3];
            x[k][2] = make_float2(u.x + t.x, u.y + t.y);
            d = make_float2(u.x - t.x, u.y - t.y);
            x[k][3] = make_float2(d.x * c - d.y * s, d.x * s + d.y * c);
        }
    }
    #pragma unroll
    for (int hbit = 5; hbit >= 0; hbit--) {
        int h = 1 << hbit;
        int j = lane & (h - 1);
        float s, c;
        __sincosf(-PI * (float)j / (float)h, &s, &c);
        bool up = (lane & h) != 0;
        #pragma unroll
        for (int k = 0; k < K; k++) {
            #pragma unroll
            for (int i = 0; i < 4; i++) {
                float px = __shfl_xor(x[k][i].x, h);
                float py = __shfl_xor(x[k][i].y, h);
                if (up) {
                    float dx = px - x[k][i].x, dy = py - x[k][i].y;
                    x[k][i] = make_float2(dx * c - dy * s, dx * s + dy * c);
                } else {
                    x[k][i] = make_float2(x[k][i].x + px, x[k][i].y + py);
                }
            }
        }
    }
}

// ---------------------------------------------------------------------------
// Fused prep (R9-proven).
// ---------------------------------------------------------------------------
__global__ __launch_bounds__(1024) void prep_all(
    const int* __restrict__ rr, const int* __restrict__ cc,
    const int* __restrict__ seg, int n,
    int* __restrict__ starts, int* __restrict__ b_pack, float* __restrict__ acc)
{
    __shared__ int cnt[128];
    __shared__ int cur[128];
    int tid = threadIdx.x;
    if (tid < NSEG * 3) acc[tid] = 0.f;
    if (tid < 128) cnt[tid] = 0;
    __syncthreads();
    for (int i = tid; i < n; i += 1024) {
        int c = cc[i], r = rr[i];
        if ((c > 128) || (c == 128 && r > 128)) atomicAdd(&cnt[255 - c], 1);
    }
    __syncthreads();
    if (tid < 64) {
        int2 c2 = reinterpret_cast<const int2*>(cnt)[tid];
        int lsum = c2.x + c2.y;
        int pre = lsum;
        #pragma unroll
        for (int off = 1; off < 64; off <<= 1) {
            int v = __shfl_up(pre, off);
            if (tid >= off) pre += v;
        }
        int excl = pre - lsum;
        int2 outv = make_int2(excl, excl + c2.x);
        reinterpret_cast<int2*>(cur)[tid] = outv;
        reinterpret_cast<int2*>(starts)[tid] = outv;
        if (tid == 63) starts[128] = excl + c2.x + c2.y;
    }
    __syncthreads();
    for (int i = tid; i < n; i += 1024) {
        int c = cc[i], r = rr[i];
        if ((c > 128) || (c == 128 && r > 128)) {
            int j = 255 - c;
            int pos = atomicAdd(&cur[j], 1);
            int pr = (int)bitrev8((unsigned)r);
            int pm = (int)bitrev8((unsigned)(256 - r) & 255);
            b_pack[pos] = pr | (pm << 8) | (seg[i] << 16);
        }
    }
}

// ---------------------------------------------------------------------------
// Row-pass (R9-proven): fp16 Gt, physical row q holds X[bitrev8(q)], x-major.
// ---------------------------------------------------------------------------
__global__ __launch_bounds__(512) void rowfft_kernel(
    const float* __restrict__ inp, const float* __restrict__ tgt,
    __half2* __restrict__ G, int pair_base)
{
    __shared__ float2 T[256 * 17];
    int bid    = blockIdx.x;
    int plocal = bid >> 4;
    int rowgrp = bid & 15;
    int wv     = threadIdx.x >> 6;
    int lane   = threadIdx.x & 63;
    size_t base = (((size_t)(pair_base + plocal)) << 16)
                + ((size_t)((rowgrp << 4) + (wv << 1)) << 8);
    const float* s1 = inp + base;
    const float* s2 = tgt + base;

    float2 x[2][4];
    #pragma unroll
    for (int k = 0; k < 2; k++)
        #pragma unroll
        for (int i = 0; i < 4; i++) {
            int e = (k << 8) + i * 64 + lane;
            x[k][i] = make_float2(s1[e], s2[e]);
        }
    fftK<2>(x, lane);

    #pragma unroll
    for (int k = 0; k < 2; k++)
        #pragma unroll
        for (int i = 0; i < 4; i++)
            T[(i * 64 + lane) * 17 + (wv << 1) + k] = x[k][i];
    __syncthreads();

    __half2* dst = G + (((size_t)plocal) << 16) + (rowgrp << 4);
    int xl = threadIdx.x & 15;
    int qb = threadIdx.x >> 4;
    #pragma unroll
    for (int ii = 0; ii < 8; ii++) {
        int q = qb + (ii << 5);
        float2 v = T[q * 17 + xl];
        dst[q * 256 + xl] = __float22half2_rn(v);
    }
}

// ---------------------------------------------------------------------------
// Column-pass + gather. 512 thr = 8 waves; 4 blocks/pair (768 blocks total).
// Wave owns 4 buckets = 2 rounds of fftK<4>; all 32 G loads prefetched.
// ---------------------------------------------------------------------------
__global__ __launch_bounds__(512) void colfft_gather_kernel(
    const __half2* __restrict__ G, const int* __restrict__ starts,
    const int* __restrict__ b_pack, float* __restrict__ acc)
{
    __shared__ float2 Fb[8][512];                // 32 KiB
    __shared__ float accl[NSEG * 3];
    int tid    = threadIdx.x;
    int wv     = tid >> 6;
    int lane   = tid & 63;
    int plocal = blockIdx.x >> 2;
    int b      = blockIdx.x & 3;

    for (int i = tid; i < NSEG * 3; i += 512) accl[i] = 0.f;
    __syncthreads();

    const __half2* Gp = G + (((size_t)plocal) << 16);
    int jb0 = (b << 5) + (wv << 2);              // wave buckets [jb0, jb0+4)

    __half2 h[2][4][4];
    #pragma unroll
    for (int rd = 0; rd < 2; rd++) {
        int jb = jb0 + (rd << 1);
        int cols[4] = { jb + 1, 255 - jb, jb + 2, 254 - jb };
        #pragma unroll
        for (int k = 0; k < 4; k++) {
            int q = (int)bitrev8((unsigned)cols[k]);
            const __half2* col = Gp + ((size_t)q << 8);
            #pragma unroll
            for (int i = 0; i < 4; i++) h[rd][k][i] = col[i * 64 + lane];
        }
    }

    float2* slot = &Fb[wv][0];
    #pragma unroll
    for (int rd = 0; rd < 2; rd++) {
        float2 x[4][4];
        #pragma unroll
        for (int k = 0; k < 4; k++)
            #pragma unroll
            for (int i = 0; i < 4; i++)
                x[k][i] = __half22float2(h[rd][k][i]);
        fftK<4>(x, lane);
        int jb = jb0 + (rd << 1);
        #pragma unroll
        for (int kb = 0; kb < 2; kb++) {
            #pragma unroll
            for (int i = 0; i < 4; i++) {
                slot[i * 64 + lane]       = x[2 * kb + 0][i];  // F_lo
                slot[256 + i * 64 + lane] = x[2 * kb + 1][i];  // F_hi
            }
            int j = jb + kb;
            int s0 = starts[j], s1 = starts[j + 1];
            int e  = s0 + lane;
            int pk = (e < s1) ? b_pack[e] : 0;
            while (e < s1) {
                int e2  = e + 64;
                int pk2 = (e2 < s1) ? b_pack[e2] : 0;
                float2 a = slot[256 + (pk & 255)];
                float2 m = slot[(pk >> 8) & 255];
                int sg = pk >> 16;
                float f1x = a.x + m.x, f1y = a.y - m.y;
                float dx  = a.x - m.x, dy  = a.y + m.y;
                atomicAdd(&accl[sg * 3 + 0], f1x * dy - f1y * dx);
                atomicAdd(&accl[sg * 3 + 1], f1x * f1x + f1y * f1y);
                atomicAdd(&accl[sg * 3 + 2], dx * dx + dy * dy);
                e = e2; pk = pk2;
            }
        }
    }
    __syncthreads();

    for (int i = tid; i < NSEG * 3; i += 512) {
        float v = accl[i];
        if (v != 0.f) atomicAdd(&acc[i], v);
    }
}

// ---------------------------------------------------------------------------
// PROBE A: identical geometry/loads + both FFT rounds, NO gather.
// ---------------------------------------------------------------------------
__global__ __launch_bounds__(512) void probe_fft(
    const __half2* __restrict__ G, float* __restrict__ scratch)
{
    int tid    = threadIdx.x;
    int wv     = tid >> 6;
    int lane   = tid & 63;
    int plocal = blockIdx.x >> 2;
    int b      = blockIdx.x & 3;
    const __half2* Gp = G + (((size_t)plocal) << 16);
    int jb0 = (b << 5) + (wv << 2);

    float acc = 0.f;
    #pragma unroll
    for (int rd = 0; rd < 2; rd++) {
        int jb = jb0 + (rd << 1);
        int cols[4] = { jb + 1, 255 - jb, jb + 2, 254 - jb };
        float2 x[4][4];
        #pragma unroll
        for (int k = 0; k < 4; k++) {
            int q = (int)bitrev8((unsigned)cols[k]);
            const __half2* col = Gp + ((size_t)q << 8);
            #pragma unroll
            for (int i = 0; i < 4; i++) x[k][i] = __half22float2(col[i * 64 + lane]);
        }
        fftK<4>(x, lane);
        #pragma unroll
        for (int k = 0; k < 4; k++)
            #pragma unroll
            for (int i = 0; i < 4; i++) acc += x[k][i].x + x[k][i].y;
    }
    scratch[(size_t)blockIdx.x * 512 + tid] = acc;
}

// ---------------------------------------------------------------------------
// PROBE C: identical geometry/loads + gather, NO FFT (raw loaded values).
// ---------------------------------------------------------------------------
__global__ __launch_bounds__(512) void probe_gather(
    const __half2* __restrict__ G, const int* __restrict__ starts,
    const int* __restrict__ b_pack, float* __restrict__ scratch)
{
    __shared__ float2 Fb[8][512];
    __shared__ float accl[NSEG * 3];
    int tid    = threadIdx.x;
    int wv     = tid >> 6;
    int lane   = tid & 63;
    int plocal = blockIdx.x >> 2;
    int b      = blockIdx.x & 3;

    for (int i = tid; i < NSEG * 3; i += 512) accl[i] = 0.f;
    __syncthreads();

    const __half2* Gp = G + (((size_t)plocal) << 16);
    int jb0 = (b << 5) + (wv << 2);
    float2* slot = &Fb[wv][0];

    #pragma unroll
    for (int rd = 0; rd < 2; rd++) {
        int jb = jb0 + (rd << 1);
        int cols[4] = { jb + 1, 255 - jb, jb + 2, 254 - jb };
        float2 x[4][4];
        #pragma unroll
        for (int k = 0; k < 4; k++) {
            int q = (int)bitrev8((unsigned)cols[k]);
            const __half2* col = Gp + ((size_t)q << 8);
            #pragma unroll
            for (int i = 0; i < 4; i++) x[k][i] = __half22float2(col[i * 64 + lane]);
        }
        // NO fftK
        #pragma unroll
        for (int kb = 0; kb < 2; kb++) {
            #pragma unroll
            for (int i = 0; i < 4; i++) {
                slot[i * 64 + lane]       = x[2 * kb + 0][i];
                slot[256 + i * 64 + lane] = x[2 * kb + 1][i];
            }
            int j = jb + kb;
            int s0 = starts[j], s1 = starts[j + 1];
            int e  = s0 + lane;
            int pk = (e < s1) ? b_pack[e] : 0;
            while (e < s1) {
                int e2  = e + 64;
                int pk2 = (e2 < s1) ? b_pack[e2] : 0;
                float2 a = slot[256 + (pk & 255)];
                float2 m = slot[(pk >> 8) & 255];
                int sg = pk >> 16;
                float f1x = a.x + m.x, f1y = a.y - m.y;
                float dx  = a.x - m.x, dy  = a.y + m.y;
                atomicAdd(&accl[sg * 3 + 0], f1x * dy - f1y * dx);
                atomicAdd(&accl[sg * 3 + 1], f1x * f1x + f1y * f1y);
                atomicAdd(&accl[sg * 3 + 2], dx * dx + dy * dy);
                e = e2; pk = pk2;
            }
        }
    }
    __syncthreads();
    float* prow = scratch + (size_t)blockIdx.x * 384;
    for (int i = tid; i < NSEG * 3; i += 512) prow[i] = accl[i];
}

// ---------------------------------------------------------------------------
__global__ void final_kernel(const float* __restrict__ acc, const float* __restrict__ w,
                             float* __restrict__ out, float scale) {
    int lane = threadIdx.x;
    float val = 0.f;
    for (int s = lane; s < NSEG; s += 64) {
        float cr = acc[s * 3 + 0];
        float p1 = acc[s * 3 + 1];
        float p2 = acc[s * 3 + 2];
        float den = p1 * p2;
        float curve = den > 0.f ? fabsf(cr) * rsqrtf(den) : 0.f;
        val += curve * w[s + 1];
    }
    if (lane == 0) val += w[0];
    #pragma unroll
    for (int off = 32; off > 0; off >>= 1) val += __shfl_down(val, off);
    if (lane == 0) out[0] = scale * val;
}

// ---------------------------------------------------------------------------
extern "C" void kernel_launch(void* const* d_in, const int* in_sizes, int n_in,
                              void* d_out, int out_size, void* d_ws, size_t ws_size,
                              hipStream_t stream)
{
    const float* inp = (const float*)d_in[0];
    const float* tgt = (const float*)d_in[1];
    const float* wts = (const float*)d_in[2];
    const int*   rr  = (const int*)d_in[3];
    const int*   cc  = (const int*)d_in[4];
    const int*   sg  = (const int*)d_in[5];
    int npts   = in_sizes[3];
    int npairs = in_sizes[0] >> 16;               // B*C (65536 px/img)

    char* ws = (char*)d_ws;
    float* acc    = (float*)(ws + 0);             // 378 floats
    int*   starts = (int*)(ws + 2048);            // 129 ints
    int*   b_pack = (int*)(ws + 4096);
    size_t paoff = 4096 + (size_t)npts * 4;
    paoff = (paoff + 255) & ~(size_t)255;
    float* pscrA = (float*)(ws + paoff);          // 768*512 floats
    size_t pcoff = paoff + (size_t)768 * 512 * 4;
    float* pscrC = (float*)(ws + pcoff);          // 768*384 floats
    size_t goff = pcoff + (size_t)768 * 384 * 4;
    goff = (goff + 255) & ~(size_t)255;
    __half2* G = (__half2*)(ws + goff);

    size_t per_pair = (size_t)256 * 256 * sizeof(__half2);  // 256 KiB
    int maxchunk = (int)((ws_size > goff ? (ws_size - goff) : 0) / per_pair);
    if (maxchunk < 1) maxchunk = 1;
    if (maxchunk > npairs) maxchunk = npairs;

    prep_all<<<1, 1024, 0, stream>>>(rr, cc, sg, npts, starts, b_pack, acc);

    for (int pb = 0; pb < npairs; pb += maxchunk) {
        int cp = npairs - pb < maxchunk ? npairs - pb : maxchunk;
        rowfft_kernel<<<cp * 16, 512, 0, stream>>>(inp, tgt, G, pb);
        colfft_gather_kernel<<<cp * 4, 512, 0, stream>>>(G, starts, b_pack, acc);
        if (pb == 0) {   // decomposition probes on first chunk's G
            probe_fft<<<cp * 4, 512, 0, stream>>>(G, pscrA);
            probe_gather<<<cp * 4, 512, 0, stream>>>(G, starts, b_pack, pscrC);
        }
    }

    final_kernel<<<1, 64, 0, stream>>>(acc, wts, (float*)d_out, (float)npairs);
}